// Round 5
// baseline (521.770 us; speedup 1.0000x reference)
//
#include <hip/hip_runtime.h>
#include <hip/hip_bf16.h>

#define NCH 64
#define SPAN 64            // dst nodes per bucket (dl fits in 6 bits)
#define BIN_BLOCKS 128
#define BIN_THREADS 1024
#define HIST_BLOCKS 256

// ---------------------------------------------------------------------------
// Block 0: dtype detection (flags[0]=fp32?, flags[1]=int64?).
// Other blocks: zero the bucket-count array (ws is poisoned 0xAA each call).
// ---------------------------------------------------------------------------
__global__ void detect_init_kernel(const unsigned short* __restrict__ gp, int n16,
                                   const unsigned* __restrict__ ip, int niw,
                                   unsigned* __restrict__ flags,
                                   unsigned* __restrict__ gcnt, int nb) {
    if (blockIdx.x == 0) {
        __shared__ unsigned se, so;
        if (threadIdx.x == 0) { se = 0u; so = 0u; }
        __syncthreads();
        unsigned le = 0u, lo = 0u;
        // fp32 viewed as shorts: ~12.5% show "bf16 exponent" >= 0xC0 (|x|>=2^65).
        // Genuine bf16 N(0,1): none.
        for (int i = threadIdx.x; i < n16; i += blockDim.x) {
            unsigned ex = (unsigned)((gp[i] >> 7) & 0xFFu);
            if (ex >= 0xC0u) le++;
        }
        // int64 ids (<2^31): every odd 32-bit word is 0. int32 ids: not.
        for (int i = threadIdx.x; i < niw; i += blockDim.x) {
            if ((i & 1) && ip[i] != 0u) lo++;
        }
        atomicAdd(&se, le);
        atomicAdd(&so, lo);
        __syncthreads();
        if (threadIdx.x == 0) {
            flags[0] = (se > 50u) ? 1u : 0u;
            flags[1] = (so < 50u) ? 1u : 0u;
        }
    } else {
        const int stride = (gridDim.x - 1) * blockDim.x;
        for (int i = (blockIdx.x - 1) * blockDim.x + threadIdx.x; i < nb; i += stride)
            gcnt[i] = 0u;
    }
}

// ---------------------------------------------------------------------------
// Bucket histogram: LDS pre-aggregation, then one global atomic per bucket
// per block (256 x nb instead of 800k scattered atomics).
// ---------------------------------------------------------------------------
__global__ void bucket_hist_kernel(const void* __restrict__ dstp,
                                   unsigned* __restrict__ gcnt,
                                   const unsigned* __restrict__ flags,
                                   int n_edges, int nb) {
    extern __shared__ unsigned lcnt[];                  // nb entries
    for (int i = threadIdx.x; i < nb; i += blockDim.x) lcnt[i] = 0u;
    __syncthreads();
    const unsigned i64 = flags[1];
    const int stride = gridDim.x * blockDim.x;
    for (int e = blockIdx.x * blockDim.x + threadIdx.x; e < n_edges; e += stride) {
        int d = i64 ? (int)((const long long*)dstp)[e] : ((const int*)dstp)[e];
        atomicAdd(&lcnt[d >> 6], 1u);
    }
    __syncthreads();
    for (int i = threadIdx.x; i < nb; i += blockDim.x)
        if (lcnt[i]) atomicAdd(&gcnt[i], lcnt[i]);
}

// ---------------------------------------------------------------------------
// Exclusive scan over nb (<=4096) bucket counts -> boffs (stable copy) and
// cursor (mutated by binning). Single block is fine at this size.
// ---------------------------------------------------------------------------
__global__ void bucket_scan_kernel(const unsigned* __restrict__ gcnt,
                                   unsigned* __restrict__ boffs,
                                   unsigned* __restrict__ cursor, int nb) {
    __shared__ unsigned s[1024];
    const int t = threadIdx.x;
    const int L = (nb + 1023) / 1024;
    unsigned local = 0u;
    for (int i = 0; i < L; ++i) {
        int idx = t * L + i;
        if (idx < nb) local += gcnt[idx];
    }
    s[t] = local;
    __syncthreads();
    for (int off = 1; off < 1024; off <<= 1) {
        unsigned v = (t >= off) ? s[t - off] : 0u;
        __syncthreads();
        s[t] += v;
        __syncthreads();
    }
    unsigned run = s[t] - local;
    for (int i = 0; i < L; ++i) {
        int idx = t * L + i;
        if (idx < nb) { boffs[idx] = run; cursor[idx] = run; run += gcnt[idx]; }
    }
}

// ---------------------------------------------------------------------------
// Binning: scatter packed (dl<<26 | src) into bucket-grouped order.
// LDS staging (depth entries/bucket) so global stores flush in contiguous
// runs (near-full cache lines) instead of 800k isolated 4B stores.
// Overflow (staging full) falls back to a direct cursor store — correct,
// order within a bucket is irrelevant.
// ---------------------------------------------------------------------------
__global__ __launch_bounds__(BIN_THREADS)
void binning_kernel(const void* __restrict__ srcp, const void* __restrict__ dstp,
                    unsigned* __restrict__ cursor, unsigned* __restrict__ sorted,
                    const unsigned* __restrict__ flags, int n_edges, int nb, int depth) {
    extern __shared__ unsigned lds[];        // [nb] lcnt, then [nb*depth] stage
    unsigned* lcnt = lds;
    unsigned* stage = lds + nb;
    for (int i = threadIdx.x; i < nb; i += blockDim.x) lcnt[i] = 0u;
    __syncthreads();
    const unsigned i64 = flags[1];
    const int chunk = (n_edges + gridDim.x - 1) / gridDim.x;
    const int e0 = blockIdx.x * chunk;
    const int e1 = min(e0 + chunk, n_edges);
    for (int e = e0 + threadIdx.x; e < e1; e += blockDim.x) {
        int s, d;
        if (i64) {
            s = (int)((const long long*)srcp)[e];
            d = (int)((const long long*)dstp)[e];
        } else {
            s = ((const int*)srcp)[e];
            d = ((const int*)dstp)[e];
        }
        const int b = d >> 6;
        const unsigned pk = ((unsigned)(d & 63) << 26) | (unsigned)s;
        unsigned pos = atomicAdd(&lcnt[b], 1u);
        if ((int)pos < depth) {
            stage[b * depth + (int)pos] = pk;
        } else {
            unsigned g = atomicAdd(&cursor[b], 1u);
            sorted[g] = pk;
        }
    }
    __syncthreads();
    for (int b = threadIdx.x; b < nb; b += blockDim.x) {
        int k = min((int)lcnt[b], depth);
        if (k > 0) {
            unsigned base = atomicAdd(&cursor[b], (unsigned)k);
            for (int i = 0; i < k; ++i) sorted[base + i] = stage[b * depth + i];
        }
    }
}

// ---------------------------------------------------------------------------
// Fused GEMM: rows 0..N-1 -> P = G @ W^T ; rows N..2N-1 -> Q' = RSC @ W^T - b.
// 4 rows per wave-iteration; output stored in input dtype (bf16 -> halves
// bucket_agg gather traffic).
// ---------------------------------------------------------------------------
__global__ void gemm2_kernel(const void* __restrict__ Gp, const void* __restrict__ Rp,
                             const void* __restrict__ Wp, const void* __restrict__ bp,
                             void* __restrict__ PQ,
                             const unsigned* __restrict__ flags, int n_nodes) {
    const unsigned f32 = flags[0];
    const int lane = threadIdx.x & 63;
    const int waveInBlk = threadIdx.x >> 6;
    const int wavesPerBlk = blockDim.x >> 6;
    const int gwave = blockIdx.x * wavesPerBlk + waveInBlk;
    const int nwaves = gridDim.x * wavesPerBlk;
    const int n_rows = 2 * n_nodes;
    const int ngroups = (n_rows + 3) / 4;

    __shared__ float ldsb[4 * 4 * NCH];
    float* slot = &ldsb[waveInBlk * 4 * NCH];

    float w[NCH];
    float bias;
    if (f32) {
        const float* Wf = (const float*)Wp;
        #pragma unroll
        for (int k = 0; k < NCH; ++k) w[k] = Wf[lane * NCH + k];
        bias = ((const float*)bp)[lane];
    } else {
        const __hip_bfloat16* Wh = (const __hip_bfloat16*)Wp;
        #pragma unroll
        for (int k = 0; k < NCH; ++k) w[k] = __bfloat162float(Wh[lane * NCH + k]);
        bias = __bfloat162float(((const __hip_bfloat16*)bp)[lane]);
    }

    const int niter = (ngroups + nwaves - 1) / nwaves;
    for (int it = 0; it < niter; ++it) {
        const int grp = gwave + it * nwaves;
        const bool gvalid = (grp < ngroups);
        const int m0 = grp * 4;
        if (gvalid) {
            const int myrow = m0 + (lane >> 4);
            const int col = (lane & 15) * 4;
            float x0 = 0.f, x1 = 0.f, x2 = 0.f, x3 = 0.f;
            if (myrow < n_rows) {
                const bool isQ = (myrow >= n_nodes);
                const int r = isQ ? (myrow - n_nodes) : myrow;
                const void* inp = isQ ? Rp : Gp;
                if (f32) {
                    float4 v = *(const float4*)((const float*)inp + (size_t)r * NCH + col);
                    x0 = v.x; x1 = v.y; x2 = v.z; x3 = v.w;
                } else {
                    ushort4 v = *(const ushort4*)((const unsigned short*)inp +
                                                  (size_t)r * NCH + col);
                    x0 = __bfloat162float(*(__hip_bfloat16*)&v.x);
                    x1 = __bfloat162float(*(__hip_bfloat16*)&v.y);
                    x2 = __bfloat162float(*(__hip_bfloat16*)&v.z);
                    x3 = __bfloat162float(*(__hip_bfloat16*)&v.w);
                }
            }
            const int sb = (lane >> 4) * NCH + col;
            slot[sb + 0] = x0; slot[sb + 1] = x1; slot[sb + 2] = x2; slot[sb + 3] = x3;
        }
        __syncthreads();
        if (gvalid) {
            #pragma unroll
            for (int rr = 0; rr < 4; ++rr) {
                const int m = m0 + rr;
                if (m < n_rows) {
                    float a0 = 0.f, a1 = 0.f, a2 = 0.f, a3 = 0.f;
                    const float4* r4 = (const float4*)(slot + rr * NCH);
                    #pragma unroll
                    for (int q = 0; q < 16; ++q) {
                        float4 rv = r4[q];
                        a0 = fmaf(rv.x, w[4 * q + 0], a0);
                        a1 = fmaf(rv.y, w[4 * q + 1], a1);
                        a2 = fmaf(rv.z, w[4 * q + 2], a2);
                        a3 = fmaf(rv.w, w[4 * q + 3], a3);
                    }
                    float acc = (a0 + a1) + (a2 + a3);
                    if (m >= n_nodes) acc -= bias;
                    if (f32) ((float*)PQ)[(size_t)m * NCH + lane] = acc;
                    else ((__hip_bfloat16*)PQ)[(size_t)m * NCH + lane] =
                             __float2bfloat16(acc);
                }
            }
        }
        __syncthreads();
    }
}

// ---------------------------------------------------------------------------
// Bucket aggregation: block = bucket of 64 dst nodes. Q' rows + max/sum
// accumulators + deg counts in LDS (48.3 KB -> 3 blocks/CU). Per edge:
// coalesced P-row gather (lane=channel) + 2 LDS atomics (relu>=0 makes
// uint atomicMax correct; banks alias 2-way = free). Writes output directly.
// ---------------------------------------------------------------------------
__global__ __launch_bounds__(256)
void bucket_agg_kernel(const void* __restrict__ PQ,
                       const unsigned* __restrict__ sorted,
                       const unsigned* __restrict__ boffs,
                       const unsigned* __restrict__ gcnt,
                       const unsigned* __restrict__ flags,
                       void* __restrict__ outp, int n_nodes) {
    __shared__ float qv[SPAN * NCH];
    __shared__ unsigned mx[SPAN * NCH];
    __shared__ float sm[SPAN * NCH];
    __shared__ unsigned dcnt[SPAN];
    const unsigned f32 = flags[0];
    const int b = blockIdx.x;
    const int base = b * SPAN;
    const int tid = threadIdx.x;
    const float* Pf = (const float*)PQ;
    const unsigned short* Ph = (const unsigned short*)PQ;

    for (int idx = tid; idx < SPAN * NCH; idx += 256) {
        const int i = idx >> 6;
        const int n = base + i;
        float q = 0.0f;
        if (n < n_nodes) {
            const size_t ofs = (size_t)(n_nodes + n) * NCH + (idx & 63);
            if (f32) q = Pf[ofs];
            else { unsigned short h = Ph[ofs]; q = __bfloat162float(*(__hip_bfloat16*)&h); }
        }
        qv[idx] = q;
        mx[idx] = 0u;
        sm[idx] = 0.0f;
        if (idx < SPAN) dcnt[idx] = 0u;
    }
    __syncthreads();

    const int estart = (int)boffs[b];
    const int eend = estart + (int)gcnt[b];
    const int lane = tid & 63;
    const int wv = tid >> 6;

    // align quad loop to 16B boundary of `sorted`
    int a0 = (estart + 3) & ~3;
    if (a0 > eend) a0 = eend;
    // prefix scalars
    for (int j = estart + wv; j < a0; j += 4) {
        const unsigned p = sorted[j];
        const int s = (int)(p & 0x03FFFFFFu);
        const int dl = (int)(p >> 26);
        float pv;
        if (f32) pv = Pf[(size_t)s * NCH + lane];
        else { unsigned short h = Ph[(size_t)s * NCH + lane];
               pv = __bfloat162float(*(__hip_bfloat16*)&h); }
        const float v = fmaxf(pv - qv[dl * NCH + lane], 0.0f);
        atomicMax(&mx[dl * NCH + lane], __float_as_uint(v));
        atomicAdd(&sm[dl * NCH + lane], v);
        if (lane == 0) atomicAdd(&dcnt[dl], 1u);
    }
    const int nq = (eend - a0) >> 2;
    for (int q4 = wv; q4 < nq; q4 += 4) {
        const int j = a0 + q4 * 4;
        const uint4 pk = *(const uint4*)&sorted[j];    // 16B-aligned broadcast
        #pragma unroll
        for (int r = 0; r < 4; ++r) {
            const unsigned p = (&pk.x)[r];
            const int s = (int)(p & 0x03FFFFFFu);
            const int dl = (int)(p >> 26);
            float pv;
            if (f32) pv = Pf[(size_t)s * NCH + lane];
            else { unsigned short h = Ph[(size_t)s * NCH + lane];
                   pv = __bfloat162float(*(__hip_bfloat16*)&h); }
            const float v = fmaxf(pv - qv[dl * NCH + lane], 0.0f);
            atomicMax(&mx[dl * NCH + lane], __float_as_uint(v));
            atomicAdd(&sm[dl * NCH + lane], v);
            if (lane == 0) atomicAdd(&dcnt[dl], 1u);
        }
    }
    // tail scalars
    for (int j = a0 + nq * 4 + wv; j < eend; j += 4) {
        const unsigned p = sorted[j];
        const int s = (int)(p & 0x03FFFFFFu);
        const int dl = (int)(p >> 26);
        float pv;
        if (f32) pv = Pf[(size_t)s * NCH + lane];
        else { unsigned short h = Ph[(size_t)s * NCH + lane];
               pv = __bfloat162float(*(__hip_bfloat16*)&h); }
        const float v = fmaxf(pv - qv[dl * NCH + lane], 0.0f);
        atomicMax(&mx[dl * NCH + lane], __float_as_uint(v));
        atomicAdd(&sm[dl * NCH + lane], v);
        if (lane == 0) atomicAdd(&dcnt[dl], 1u);
    }
    __syncthreads();

    for (int idx = tid; idx < SPAN * NCH; idx += 256) {
        const int i = idx >> 6;
        const int n = base + i;
        if (n < n_nodes) {
            const int c = idx & 63;
            const float mxv = __uint_as_float(mx[idx]);
            const unsigned dg = dcnt[i];
            const float avg = sm[idx] / (float)(dg ? dg : 1u);
            if (f32) {
                ((float*)outp)[(size_t)n * 2 * NCH + c] = mxv;
                ((float*)outp)[(size_t)n * 2 * NCH + NCH + c] = avg;
            } else {
                ((__hip_bfloat16*)outp)[(size_t)n * 2 * NCH + c] = __float2bfloat16(mxv);
                ((__hip_bfloat16*)outp)[(size_t)n * 2 * NCH + NCH + c] = __float2bfloat16(avg);
            }
        }
    }
}

extern "C" void kernel_launch(void* const* d_in, const int* in_sizes, int n_in,
                              void* d_out, int out_size, void* d_ws, size_t ws_size,
                              hipStream_t stream) {
    const void* G = d_in[0];
    const void* RSC = d_in[1];
    const void* src = d_in[2];
    const void* dst = d_in[3];
    const void* W = d_in[4];
    const void* b = d_in[5];

    const int n_nodes = in_sizes[0] / NCH;
    const int n_edges = in_sizes[2];
    const int nb = (n_nodes + SPAN - 1) / SPAN;     // buckets

    // ws layout (bytes):
    //  [flags 256][sorted 4E pad][boffs 4nb pad][cursor 4nb pad][gcnt 4nb pad][PQ]
    char* ws = (char*)d_ws;
    unsigned* flags = (unsigned*)ws;
    size_t off = 256;
    unsigned* sorted = (unsigned*)(ws + off);
    off += (((size_t)n_edges * 4 + 255) / 256) * 256;
    unsigned* boffs = (unsigned*)(ws + off);
    off += (((size_t)nb * 4 + 255) / 256) * 256;
    unsigned* cursor = (unsigned*)(ws + off);
    off += (((size_t)nb * 4 + 255) / 256) * 256;
    unsigned* gcnt = (unsigned*)(ws + off);
    off += (((size_t)nb * 4 + 255) / 256) * 256;
    void* PQ = (void*)(ws + off);                   // fp32 or bf16 per flags[0]

    const int n_g_probe = (in_sizes[0] < 8192) ? in_sizes[0] : 8192;
    const int n_idx_probe = (n_edges < 8192) ? n_edges : 8192;

    detect_init_kernel<<<64, 256, 0, stream>>>((const unsigned short*)G, n_g_probe,
                                               (const unsigned*)src, n_idx_probe,
                                               flags, gcnt, nb);

    bucket_hist_kernel<<<HIST_BLOCKS, 256, (size_t)nb * 4, stream>>>(
        dst, gcnt, flags, n_edges, nb);

    bucket_scan_kernel<<<1, 1024, 0, stream>>>(gcnt, boffs, cursor, nb);

    int depth = 16384 / nb - 1;                     // keep dyn LDS <= 64 KB
    if (depth > 19) depth = 19;
    if (depth < 4) depth = 4;
    const size_t bin_lds = (size_t)nb * (depth + 1) * 4;
    binning_kernel<<<BIN_BLOCKS, BIN_THREADS, bin_lds, stream>>>(
        src, dst, cursor, sorted, flags, n_edges, nb, depth);

    gemm2_kernel<<<2048, 256, 0, stream>>>(G, RSC, W, b, PQ, flags, n_nodes);

    bucket_agg_kernel<<<nb, 256, 0, stream>>>(PQ, sorted, boffs, gcnt, flags,
                                              d_out, n_nodes);
}

// Round 6
// 199.942 us; speedup vs baseline: 2.6096x; 2.6096x over previous
//
#include <hip/hip_runtime.h>
#include <hip/hip_bf16.h>

#define NCH 64
#define SPAN 64            // dst nodes per bucket (dl fits in 6 bits)
#define BIN_BLOCKS 128
#define BIN_THREADS 1024
#define HIST_BLOCKS 256
#define SORT_CAP 3072      // LDS staging capacity per bucket in bucket_sort

// ---------------------------------------------------------------------------
// Block 0: dtype detection (flags[0]=fp32?, flags[1]=int64?).
// Other blocks: zero the bucket-count array (ws is poisoned 0xAA each call).
// ---------------------------------------------------------------------------
__global__ void detect_init_kernel(const unsigned short* __restrict__ gp, int n16,
                                   const unsigned* __restrict__ ip, int niw,
                                   unsigned* __restrict__ flags,
                                   unsigned* __restrict__ gcnt, int nb) {
    if (blockIdx.x == 0) {
        __shared__ unsigned se, so;
        if (threadIdx.x == 0) { se = 0u; so = 0u; }
        __syncthreads();
        unsigned le = 0u, lo = 0u;
        // fp32 viewed as shorts: ~12.5% show "bf16 exponent" >= 0xC0 (|x|>=2^65).
        // Genuine bf16 N(0,1): none.
        for (int i = threadIdx.x; i < n16; i += blockDim.x) {
            unsigned ex = (unsigned)((gp[i] >> 7) & 0xFFu);
            if (ex >= 0xC0u) le++;
        }
        // int64 ids (<2^31): every odd 32-bit word is 0. int32 ids: not.
        for (int i = threadIdx.x; i < niw; i += blockDim.x) {
            if ((i & 1) && ip[i] != 0u) lo++;
        }
        atomicAdd(&se, le);
        atomicAdd(&so, lo);
        __syncthreads();
        if (threadIdx.x == 0) {
            flags[0] = (se > 50u) ? 1u : 0u;
            flags[1] = (so < 50u) ? 1u : 0u;
        }
    } else {
        const int stride = (gridDim.x - 1) * blockDim.x;
        for (int i = (blockIdx.x - 1) * blockDim.x + threadIdx.x; i < nb; i += stride)
            gcnt[i] = 0u;
    }
}

// ---------------------------------------------------------------------------
// Bucket histogram: LDS pre-aggregation (nb counters), one global atomic per
// bucket per block instead of 800k random global RMWs.
// ---------------------------------------------------------------------------
__global__ void bucket_hist_kernel(const void* __restrict__ dstp,
                                   unsigned* __restrict__ gcnt,
                                   const unsigned* __restrict__ flags,
                                   int n_edges, int nb) {
    extern __shared__ unsigned lcnt[];
    for (int i = threadIdx.x; i < nb; i += blockDim.x) lcnt[i] = 0u;
    __syncthreads();
    const unsigned i64 = flags[1];
    const int stride = gridDim.x * blockDim.x;
    for (int e = blockIdx.x * blockDim.x + threadIdx.x; e < n_edges; e += stride) {
        int d = i64 ? (int)((const long long*)dstp)[e] : ((const int*)dstp)[e];
        atomicAdd(&lcnt[d >> 6], 1u);
    }
    __syncthreads();
    for (int i = threadIdx.x; i < nb; i += blockDim.x)
        if (lcnt[i]) atomicAdd(&gcnt[i], lcnt[i]);
}

// ---------------------------------------------------------------------------
// Exclusive scan over nb (<=1024*L) bucket counts -> boffs (stable) + cursor.
// ---------------------------------------------------------------------------
__global__ void bucket_scan_kernel(const unsigned* __restrict__ gcnt,
                                   unsigned* __restrict__ boffs,
                                   unsigned* __restrict__ cursor, int nb) {
    __shared__ unsigned s[1024];
    const int t = threadIdx.x;
    const int L = (nb + 1023) / 1024;
    unsigned local = 0u;
    for (int i = 0; i < L; ++i) {
        int idx = t * L + i;
        if (idx < nb) local += gcnt[idx];
    }
    s[t] = local;
    __syncthreads();
    for (int off = 1; off < 1024; off <<= 1) {
        unsigned v = (t >= off) ? s[t - off] : 0u;
        __syncthreads();
        s[t] += v;
        __syncthreads();
    }
    unsigned run = s[t] - local;
    for (int i = 0; i < L; ++i) {
        int idx = t * L + i;
        if (idx < nb) { boffs[idx] = run; cursor[idx] = run; run += gcnt[idx]; }
    }
}

// ---------------------------------------------------------------------------
// Binning: scatter packed (dl<<26 | src) into bucket-grouped order.
// LDS staging (depth/bucket) -> global stores flush as contiguous runs
// (near-full cache lines). Overflow falls back to a direct cursor store.
// ---------------------------------------------------------------------------
__global__ __launch_bounds__(BIN_THREADS)
void binning_kernel(const void* __restrict__ srcp, const void* __restrict__ dstp,
                    unsigned* __restrict__ cursor, unsigned* __restrict__ binned,
                    const unsigned* __restrict__ flags, int n_edges, int nb, int depth) {
    extern __shared__ unsigned lds[];        // [nb] lcnt, then [nb*depth] stage
    unsigned* lcnt = lds;
    unsigned* stage = lds + nb;
    for (int i = threadIdx.x; i < nb; i += blockDim.x) lcnt[i] = 0u;
    __syncthreads();
    const unsigned i64 = flags[1];
    const int chunk = (n_edges + gridDim.x - 1) / gridDim.x;
    const int e0 = blockIdx.x * chunk;
    const int e1 = min(e0 + chunk, n_edges);
    for (int e = e0 + threadIdx.x; e < e1; e += blockDim.x) {
        int s, d;
        if (i64) {
            s = (int)((const long long*)srcp)[e];
            d = (int)((const long long*)dstp)[e];
        } else {
            s = ((const int*)srcp)[e];
            d = ((const int*)dstp)[e];
        }
        const int b = d >> 6;
        const unsigned pk = ((unsigned)(d & 63) << 26) | (unsigned)s;
        unsigned pos = atomicAdd(&lcnt[b], 1u);
        if ((int)pos < depth) {
            stage[b * depth + (int)pos] = pk;
        } else {
            unsigned g = atomicAdd(&cursor[b], 1u);
            binned[g] = pk;
        }
    }
    __syncthreads();
    for (int b = threadIdx.x; b < nb; b += blockDim.x) {
        int k = min((int)lcnt[b], depth);
        if (k > 0) {
            unsigned base = atomicAdd(&cursor[b], (unsigned)k);
            for (int i = 0; i < k; ++i) binned[base + i] = stage[b * depth + i];
        }
    }
}

// ---------------------------------------------------------------------------
// Bucket sort: block = bucket. Stage the bucket's packed edges in LDS, count
// the 64 per-node degrees, scan, then scatter src ids into exact per-node
// runs inside the contiguous bucket region. Emits global CSR offs:
// offs[n] = start of node n's run; offs[n_nodes] = n_edges.
// ---------------------------------------------------------------------------
__global__ __launch_bounds__(256)
void bucket_sort_kernel(const unsigned* __restrict__ binned,
                        const unsigned* __restrict__ boffs,
                        const unsigned* __restrict__ gcnt,
                        unsigned* __restrict__ sorted_src,
                        unsigned* __restrict__ offs,
                        int n_nodes, int n_edges, int nb) {
    __shared__ unsigned dcnt[SPAN];
    __shared__ unsigned doff[SPAN];
    __shared__ unsigned cur[SPAN];
    __shared__ unsigned stage[SORT_CAP];
    const int b = blockIdx.x;
    const int tid = threadIdx.x;
    const int estart = (int)boffs[b];
    const int count = (int)gcnt[b];

    if (tid < SPAN) dcnt[tid] = 0u;
    __syncthreads();

    for (int i = tid; i < count; i += 256) {
        const unsigned pk = binned[estart + i];
        atomicAdd(&dcnt[pk >> 26], 1u);
        if (i < SORT_CAP) stage[i] = pk;
    }
    __syncthreads();

    if (tid == 0) {
        unsigned run = 0u;
        #pragma unroll
        for (int i = 0; i < SPAN; ++i) { doff[i] = run; cur[i] = run; run += dcnt[i]; }
    }
    __syncthreads();

    if (tid < SPAN) {
        const int n = b * SPAN + tid;
        if (n < n_nodes) offs[n] = (unsigned)estart + doff[tid];
    }
    if (b == nb - 1 && tid == 0) offs[n_nodes] = (unsigned)n_edges;

    const int lim = (count < SORT_CAP) ? count : SORT_CAP;
    for (int i = tid; i < lim; i += 256) {
        const unsigned pk = stage[i];
        const unsigned pos = atomicAdd(&cur[pk >> 26], 1u);
        sorted_src[estart + pos] = pk & 0x03FFFFFFu;
    }
    // overflow (bucket bigger than LDS stage): re-read from binned (distinct
    // buffer from sorted_src, so no corruption)
    for (int i = SORT_CAP + tid; i < count; i += 256) {
        const unsigned pk = binned[estart + i];
        const unsigned pos = atomicAdd(&cur[pk >> 26], 1u);
        sorted_src[estart + pos] = pk & 0x03FFFFFFu;
    }
}

// ---------------------------------------------------------------------------
// Fused GEMM: rows 0..N-1 -> P = G @ W^T ; rows N..2N-1 -> Q' = RSC @ W^T - b.
// 4 rows per wave-iteration; output stored in input dtype (bf16 halves the
// node-kernel gather footprint). Unchanged from round 4.
// ---------------------------------------------------------------------------
__global__ void gemm2_kernel(const void* __restrict__ Gp, const void* __restrict__ Rp,
                             const void* __restrict__ Wp, const void* __restrict__ bp,
                             void* __restrict__ PQ,
                             const unsigned* __restrict__ flags, int n_nodes) {
    const unsigned f32 = flags[0];
    const int lane = threadIdx.x & 63;
    const int waveInBlk = threadIdx.x >> 6;
    const int wavesPerBlk = blockDim.x >> 6;
    const int gwave = blockIdx.x * wavesPerBlk + waveInBlk;
    const int nwaves = gridDim.x * wavesPerBlk;
    const int n_rows = 2 * n_nodes;
    const int ngroups = (n_rows + 3) / 4;

    __shared__ float ldsb[4 * 4 * NCH];
    float* slot = &ldsb[waveInBlk * 4 * NCH];

    float w[NCH];
    float bias;
    if (f32) {
        const float* Wf = (const float*)Wp;
        #pragma unroll
        for (int k = 0; k < NCH; ++k) w[k] = Wf[lane * NCH + k];
        bias = ((const float*)bp)[lane];
    } else {
        const __hip_bfloat16* Wh = (const __hip_bfloat16*)Wp;
        #pragma unroll
        for (int k = 0; k < NCH; ++k) w[k] = __bfloat162float(Wh[lane * NCH + k]);
        bias = __bfloat162float(((const __hip_bfloat16*)bp)[lane]);
    }

    const int niter = (ngroups + nwaves - 1) / nwaves;
    for (int it = 0; it < niter; ++it) {
        const int grp = gwave + it * nwaves;
        const bool gvalid = (grp < ngroups);
        const int m0 = grp * 4;
        if (gvalid) {
            const int myrow = m0 + (lane >> 4);
            const int col = (lane & 15) * 4;
            float x0 = 0.f, x1 = 0.f, x2 = 0.f, x3 = 0.f;
            if (myrow < n_rows) {
                const bool isQ = (myrow >= n_nodes);
                const int r = isQ ? (myrow - n_nodes) : myrow;
                const void* inp = isQ ? Rp : Gp;
                if (f32) {
                    float4 v = *(const float4*)((const float*)inp + (size_t)r * NCH + col);
                    x0 = v.x; x1 = v.y; x2 = v.z; x3 = v.w;
                } else {
                    ushort4 v = *(const ushort4*)((const unsigned short*)inp +
                                                  (size_t)r * NCH + col);
                    x0 = __bfloat162float(*(__hip_bfloat16*)&v.x);
                    x1 = __bfloat162float(*(__hip_bfloat16*)&v.y);
                    x2 = __bfloat162float(*(__hip_bfloat16*)&v.z);
                    x3 = __bfloat162float(*(__hip_bfloat16*)&v.w);
                }
            }
            const int sb = (lane >> 4) * NCH + col;
            slot[sb + 0] = x0; slot[sb + 1] = x1; slot[sb + 2] = x2; slot[sb + 3] = x3;
        }
        __syncthreads();
        if (gvalid) {
            #pragma unroll
            for (int rr = 0; rr < 4; ++rr) {
                const int m = m0 + rr;
                if (m < n_rows) {
                    float a0 = 0.f, a1 = 0.f, a2 = 0.f, a3 = 0.f;
                    const float4* r4 = (const float4*)(slot + rr * NCH);
                    #pragma unroll
                    for (int q = 0; q < 16; ++q) {
                        float4 rv = r4[q];
                        a0 = fmaf(rv.x, w[4 * q + 0], a0);
                        a1 = fmaf(rv.y, w[4 * q + 1], a1);
                        a2 = fmaf(rv.z, w[4 * q + 2], a2);
                        a3 = fmaf(rv.w, w[4 * q + 3], a3);
                    }
                    float acc = (a0 + a1) + (a2 + a3);
                    if (m >= n_nodes) acc -= bias;
                    if (f32) ((float*)PQ)[(size_t)m * NCH + lane] = acc;
                    else ((__hip_bfloat16*)PQ)[(size_t)m * NCH + lane] =
                             __float2bfloat16(acc);
                }
            }
        }
        __syncthreads();
    }
}

// ---------------------------------------------------------------------------
// One wave per node (grid-stride), lane = channel. Register-lean (VGPR ~8,
// no LDS) -> full 32 waves/CU for gather-latency hiding (round-5 lesson).
// start = offs[n], end = offs[n+1].
// ---------------------------------------------------------------------------
__global__ void node_kernel(const void* __restrict__ PQ,
                            const unsigned* __restrict__ sorted_src,
                            const unsigned* __restrict__ offs,
                            const unsigned* __restrict__ flags,
                            void* __restrict__ outp, int n_nodes) {
    const unsigned f32 = flags[0];
    const int lane = threadIdx.x & 63;
    const int gwave = (blockIdx.x * blockDim.x + threadIdx.x) >> 6;
    const int nwaves = (gridDim.x * blockDim.x) >> 6;
    const float* Pf = (const float*)PQ;
    const unsigned short* Ph = (const unsigned short*)PQ;

    for (int n = gwave; n < n_nodes; n += nwaves) {
        float q;
        if (f32) q = Pf[(size_t)(n_nodes + n) * NCH + lane];
        else {
            unsigned short h = Ph[(size_t)(n_nodes + n) * NCH + lane];
            q = __bfloat162float(*(__hip_bfloat16*)&h);
        }
        const int start = (int)offs[n];
        const int end = (int)offs[n + 1];
        float vmax = 0.0f, vsum = 0.0f;
        int j = start;
        for (; j + 4 <= end; j += 4) {
            const int s0 = (int)sorted_src[j];
            const int s1 = (int)sorted_src[j + 1];
            const int s2 = (int)sorted_src[j + 2];
            const int s3 = (int)sorted_src[j + 3];
            float p0, p1, p2, p3;
            if (f32) {
                p0 = Pf[(size_t)s0 * NCH + lane];
                p1 = Pf[(size_t)s1 * NCH + lane];
                p2 = Pf[(size_t)s2 * NCH + lane];
                p3 = Pf[(size_t)s3 * NCH + lane];
            } else {
                unsigned short h0 = Ph[(size_t)s0 * NCH + lane];
                unsigned short h1 = Ph[(size_t)s1 * NCH + lane];
                unsigned short h2 = Ph[(size_t)s2 * NCH + lane];
                unsigned short h3 = Ph[(size_t)s3 * NCH + lane];
                p0 = __bfloat162float(*(__hip_bfloat16*)&h0);
                p1 = __bfloat162float(*(__hip_bfloat16*)&h1);
                p2 = __bfloat162float(*(__hip_bfloat16*)&h2);
                p3 = __bfloat162float(*(__hip_bfloat16*)&h3);
            }
            const float v0 = fmaxf(p0 - q, 0.0f);
            const float v1 = fmaxf(p1 - q, 0.0f);
            const float v2 = fmaxf(p2 - q, 0.0f);
            const float v3 = fmaxf(p3 - q, 0.0f);
            vmax = fmaxf(fmaxf(vmax, v0), fmaxf(v1, fmaxf(v2, v3)));
            vsum += (v0 + v1) + (v2 + v3);
        }
        for (; j < end; ++j) {
            const int s = (int)sorted_src[j];
            float p;
            if (f32) p = Pf[(size_t)s * NCH + lane];
            else {
                unsigned short h = Ph[(size_t)s * NCH + lane];
                p = __bfloat162float(*(__hip_bfloat16*)&h);
            }
            const float v = fmaxf(p - q, 0.0f);
            vmax = fmaxf(vmax, v);
            vsum += v;
        }
        const int deg = end - start;
        const float avg = vsum / (float)(deg > 0 ? deg : 1);
        if (f32) {
            float* out = (float*)outp;
            out[(size_t)n * 2 * NCH + lane] = vmax;
            out[(size_t)n * 2 * NCH + NCH + lane] = avg;
        } else {
            __hip_bfloat16* out = (__hip_bfloat16*)outp;
            out[(size_t)n * 2 * NCH + lane] = __float2bfloat16(vmax);
            out[(size_t)n * 2 * NCH + NCH + lane] = __float2bfloat16(avg);
        }
    }
}

extern "C" void kernel_launch(void* const* d_in, const int* in_sizes, int n_in,
                              void* d_out, int out_size, void* d_ws, size_t ws_size,
                              hipStream_t stream) {
    const void* G = d_in[0];
    const void* RSC = d_in[1];
    const void* src = d_in[2];
    const void* dst = d_in[3];
    const void* W = d_in[4];
    const void* b = d_in[5];

    const int n_nodes = in_sizes[0] / NCH;
    const int n_edges = in_sizes[2];
    const int nb = (n_nodes + SPAN - 1) / SPAN;

    // ws layout (bytes): [flags 256][binned 4E][sorted 4E][offs 4(N+1)]
    //                    [boffs 4nb][cursor 4nb][gcnt 4nb][PQ dtype*64*2N]
    char* ws = (char*)d_ws;
    unsigned* flags = (unsigned*)ws;
    size_t off = 256;
    unsigned* binned = (unsigned*)(ws + off);
    off += (((size_t)n_edges * 4 + 255) / 256) * 256;
    unsigned* sorted_src = (unsigned*)(ws + off);
    off += (((size_t)n_edges * 4 + 255) / 256) * 256;
    unsigned* offs = (unsigned*)(ws + off);
    off += (((size_t)(n_nodes + 1) * 4 + 255) / 256) * 256;
    unsigned* boffs = (unsigned*)(ws + off);
    off += (((size_t)nb * 4 + 255) / 256) * 256;
    unsigned* cursor = (unsigned*)(ws + off);
    off += (((size_t)nb * 4 + 255) / 256) * 256;
    unsigned* gcnt = (unsigned*)(ws + off);
    off += (((size_t)nb * 4 + 255) / 256) * 256;
    void* PQ = (void*)(ws + off);                   // fp32 or bf16 per flags[0]

    const int n_g_probe = (in_sizes[0] < 8192) ? in_sizes[0] : 8192;
    const int n_idx_probe = (n_edges < 8192) ? n_edges : 8192;

    detect_init_kernel<<<64, 256, 0, stream>>>((const unsigned short*)G, n_g_probe,
                                               (const unsigned*)src, n_idx_probe,
                                               flags, gcnt, nb);

    bucket_hist_kernel<<<HIST_BLOCKS, 256, (size_t)nb * 4, stream>>>(
        dst, gcnt, flags, n_edges, nb);

    bucket_scan_kernel<<<1, 1024, 0, stream>>>(gcnt, boffs, cursor, nb);

    int depth = 16384 / nb - 1;                     // keep dyn LDS <= 64 KB
    if (depth > 19) depth = 19;
    if (depth < 4) depth = 4;
    const size_t bin_lds = (size_t)nb * (depth + 1) * 4;
    binning_kernel<<<BIN_BLOCKS, BIN_THREADS, bin_lds, stream>>>(
        src, dst, cursor, binned, flags, n_edges, nb, depth);

    bucket_sort_kernel<<<nb, 256, 0, stream>>>(binned, boffs, gcnt, sorted_src,
                                               offs, n_nodes, n_edges, nb);

    gemm2_kernel<<<2048, 256, 0, stream>>>(G, RSC, W, b, PQ, flags, n_nodes);

    node_kernel<<<2048, 256, 0, stream>>>(PQ, sorted_src, offs, flags, d_out, n_nodes);
}